// Round 2
// baseline (441.773 us; speedup 1.0000x reference)
//
#include <hip/hip_runtime.h>
#include <stdint.h>

#define NDIM 256
#define BATCH 65536
#define NROT 32640          // 256*255/2
#define PBLK 16             // parallel Givens blocks per matrix

typedef float  f32x4 __attribute__((ext_vector_type(4)));
typedef short  s16x8 __attribute__((ext_vector_type(8)));
typedef unsigned int u32x4 __attribute__((ext_vector_type(4)));
typedef unsigned int u32x2 __attribute__((ext_vector_type(2)));

// round-to-nearest-even float -> bf16 bits
static __device__ __forceinline__ unsigned short f2bf(float f) {
    unsigned int u = __float_as_uint(f);
    u += 0x7fffu + ((u >> 16) & 1u);
    return (unsigned short)(u >> 16);
}

// ---------------- workspace layout (bytes) ----------------
static constexpr size_t OFF_CS   = 0;
static constexpr size_t OFF_PING = 524288;
static constexpr size_t OFF_PONG = OFF_PING + 8388608;
static constexpr size_t OFF_ABT  = OFF_PONG + 8388608;
static constexpr size_t OFF_INV  = OFF_ABT + 262144;

// ---------------- kernel 1: cos/sin of all rotation angles ----------------
__global__ void k_cossin(const float* __restrict__ r1, const float* __restrict__ r2,
                         float2* __restrict__ cs) {
    int i = blockIdx.x * 256 + threadIdx.x;
    if (i < 2 * NROT) {
        float th = (i < NROT) ? r1[i] : r2[i - NROT];
        cs[i] = make_float2(cosf(th), sinf(th));
    }
}

// ---------------- kernel 2: build PBLK partial Givens products per matrix ----
// One thread per column, column state in LDS, active-sweep row in a register.
// cos/sin pairs are batch-staged (64 at a time) into LDS via one coalesced
// load with register prefetch, so the rotation loop never touches global.
// Single wave per WG -> no barriers required.
__global__ __launch_bounds__(64) void k_blocks(const float2* __restrict__ cs,
                                               float* __restrict__ bmats) {
    __shared__ float colb[256 * 64];
    __shared__ float2 csb[64];
    const int t = threadIdx.x;          // column within chunk
    const int chunk = blockIdx.x;       // 0..3 (64 cols each)
    const int b = blockIdx.y;           // block 0..15
    const int set = blockIdx.z;         // 0 = rots1, 1 = rots2
    const int col0 = chunk * 64;

    // sweep-aligned partition boundaries
    const int tlo = b * (NROT / PBLK);
    const int thi = (b + 1) * (NROT / PBLK);
    int s0 = -1, s1 = -1, roff = 0, rend = 0;
    {
        int cum = 0;
        for (int i = 0; i <= 255; i++) {
            if (s0 < 0 && cum >= tlo) { s0 = i; roff = cum; }
            if (s1 < 0 && cum >= thi) { s1 = i; rend = cum; }
            cum += 255 - i;
        }
        if (s1 < 0) { s1 = 255; rend = NROT; }
    }
    const int nrot = rend - roff;

    // init identity (vectorized zero + diag)
    {
        const f32x4 z = {0.f, 0.f, 0.f, 0.f};
        #pragma unroll 8
        for (int q = 0; q < 64; q++)
            *(f32x4*)&colb[(q * 64 + t) * 4] = z;
        colb[(col0 + t) * 64 + t] = 1.0f;
    }

    const float2* mycs = cs + (size_t)set * NROT + roff;
    int i = s0, jj = s0 + 1;
    float u = colb[i * 64 + t];
    float2 nx = (t < nrot) ? mycs[t] : make_float2(1.f, 0.f);

    for (int base = 0; base < nrot; base += 64) {
        csb[t] = nx;                                  // publish current batch
        int rem_next = nrot - (base + 64);
        if (t < rem_next) nx = mycs[base + 64 + t];   // prefetch next batch
        const int nb = min(64, nrot - base);
        #pragma unroll 4
        for (int k = 0; k < nb; k++) {
            float2 cv = csb[k];                       // LDS broadcast
            float rj = colb[jj * 64 + t];
            colb[jj * 64 + t] = cv.y * u + cv.x * rj; // new row j (old u)
            u = cv.x * u - cv.y * rj;                 // new row i (old rj)
            jj++;
            if (jj == 256) {                          // sweep boundary (uniform)
                colb[i * 64 + t] = u;
                i++;
                jj = i + 1;
                u = colb[i * 64 + t];
            }
        }
    }
    colb[i * 64 + t] = u;

    float* outm = bmats + (size_t)(set * PBLK + b) * 65536;
    for (int r = 0; r < 256; r++)
        outm[(size_t)r * 256 + col0 + t] = colb[r * 64 + t];
}

// ---------------- kernel 3: pairwise combine round (fp32 256^3 matmul) ------
__global__ __launch_bounds__(256) void k_combine(const float* __restrict__ src,
                                                 float* __restrict__ dst, int half) {
    const int by = blockIdx.y;
    const int set = by / half, pidx = by % half;
    const float* Am = src + (size_t)(set * 2 * half + 2 * pidx + 1) * 65536;
    const float* Bm = src + (size_t)(set * 2 * half + 2 * pidx) * 65536;
    float* Dm = dst + (size_t)(set * half + pidx) * 65536;
    const int tr = blockIdx.x >> 2, tc = blockIdx.x & 3;

    __shared__ float As[64 * 32];
    __shared__ float Bs[32 * 64];
    const int tid = threadIdx.x;
    const int tx = tid & 15, ty = tid >> 4;

    float acc[4][4] = {};
    for (int kb = 0; kb < 8; kb++) {
        __syncthreads();
        #pragma unroll
        for (int it = 0; it < 2; it++) {
            int flat = tid + it * 256;
            int r = flat >> 3, c4 = flat & 7;
            f32x4 v = *(const f32x4*)&Am[(size_t)(tr * 64 + r) * 256 + kb * 32 + c4 * 4];
            *(f32x4*)&As[r * 32 + c4 * 4] = v;
        }
        #pragma unroll
        for (int it = 0; it < 2; it++) {
            int flat = tid + it * 256;
            int r = flat >> 4, c4 = flat & 15;
            f32x4 v = *(const f32x4*)&Bm[(size_t)(kb * 32 + r) * 256 + tc * 64 + c4 * 4];
            *(f32x4*)&Bs[r * 64 + c4 * 4] = v;
        }
        __syncthreads();
        #pragma unroll 8
        for (int kk = 0; kk < 32; kk++) {
            f32x4 bv = *(const f32x4*)&Bs[kk * 64 + tx * 4];
            float a0 = As[(ty * 4 + 0) * 32 + kk];
            float a1 = As[(ty * 4 + 1) * 32 + kk];
            float a2 = As[(ty * 4 + 2) * 32 + kk];
            float a3 = As[(ty * 4 + 3) * 32 + kk];
            #pragma unroll
            for (int j = 0; j < 4; j++) {
                acc[0][j] += a0 * bv[j];
                acc[1][j] += a1 * bv[j];
                acc[2][j] += a2 * bv[j];
                acc[3][j] += a3 * bv[j];
            }
        }
    }
    #pragma unroll
    for (int i = 0; i < 4; i++) {
        f32x4 v = { acc[i][0], acc[i][1], acc[i][2], acc[i][3] };
        *(f32x4*)&Dm[(size_t)(tr * 64 + ty * 4 + i) * 256 + tc * 64 + tx * 4] = v;
    }
}

// ---------------- kernel 4: AT/BT = M2 @ diag(cos|sin(phases)) @ M1 -> bf16 -
__global__ __launch_bounds__(256) void k_abt(const float* __restrict__ mats,
                                             const float* __restrict__ phases,
                                             unsigned short* __restrict__ abt) {
    const float* Am = mats + 65536;    // M2
    const float* Bm = mats;            // M1
    const int v = blockIdx.y;          // 0: cos (AT), 1: sin (BT)
    const int tr = blockIdx.x >> 2, tc = blockIdx.x & 3;

    __shared__ float As[64 * 32];
    __shared__ float Bs[32 * 64];
    const int tid = threadIdx.x;
    const int tx = tid & 15, ty = tid >> 4;

    float acc[4][4] = {};
    for (int kb = 0; kb < 8; kb++) {
        __syncthreads();
        #pragma unroll
        for (int it = 0; it < 2; it++) {
            int flat = tid + it * 256;
            int r = flat >> 3, c4 = flat & 7;
            f32x4 vv = *(const f32x4*)&Am[(size_t)(tr * 64 + r) * 256 + kb * 32 + c4 * 4];
            *(f32x4*)&As[r * 32 + c4 * 4] = vv;
        }
        #pragma unroll
        for (int it = 0; it < 2; it++) {
            int flat = tid + it * 256;
            int r = flat >> 4, c4 = flat & 15;
            int kg = kb * 32 + r;
            float ph = phases[kg];
            float sc = v ? sinf(ph) : cosf(ph);
            f32x4 vv = *(const f32x4*)&Bm[(size_t)kg * 256 + tc * 64 + c4 * 4];
            vv[0] *= sc; vv[1] *= sc; vv[2] *= sc; vv[3] *= sc;
            *(f32x4*)&Bs[r * 64 + c4 * 4] = vv;
        }
        __syncthreads();
        #pragma unroll 8
        for (int kk = 0; kk < 32; kk++) {
            f32x4 bv = *(const f32x4*)&Bs[kk * 64 + tx * 4];
            float a0 = As[(ty * 4 + 0) * 32 + kk];
            float a1 = As[(ty * 4 + 1) * 32 + kk];
            float a2 = As[(ty * 4 + 2) * 32 + kk];
            float a3 = As[(ty * 4 + 3) * 32 + kk];
            #pragma unroll
            for (int j = 0; j < 4; j++) {
                acc[0][j] += a0 * bv[j];
                acc[1][j] += a1 * bv[j];
                acc[2][j] += a2 * bv[j];
                acc[3][j] += a3 * bv[j];
            }
        }
    }
    #pragma unroll
    for (int i = 0; i < 4; i++) {
        unsigned short h0 = f2bf(acc[i][0]), h1 = f2bf(acc[i][1]);
        unsigned short h2 = f2bf(acc[i][2]), h3 = f2bf(acc[i][3]);
        u32x2 pk = { (unsigned)h0 | ((unsigned)h1 << 16),
                     (unsigned)h2 | ((unsigned)h3 << 16) };
        *(u32x2*)&abt[(size_t)(v * 256 + tr * 64 + ty * 4 + i) * 256 + tc * 64 + tx * 4] = pk;
    }
}

// ---------------- kernel 5: per-row 1/||x|| ---------------------------------
__global__ __launch_bounds__(256) void k_norm(const float* __restrict__ x,
                                              float* __restrict__ invn) {
    const int row = blockIdx.x * 4 + (threadIdx.x >> 6);
    const int lane = threadIdx.x & 63;
    f32x4 v = *(const f32x4*)&x[(size_t)row * 256 + lane * 4];
    float s = v[0] * v[0] + v[1] * v[1] + v[2] * v[2] + v[3] * v[3];
    for (int off = 32; off; off >>= 1) s += __shfl_xor(s, off, 64);
    if (lane == 0) invn[row] = 1.0f / sqrtf(s);
}

// ---------------- kernel 6: final fused GEMM + |.|^2 epilogue ---------------
// Normalization folded into the bf16 staging (v *= invn[row]); epilogue is
// just p^2 + q^2.
#define BKP 136   // padded LDS k-stride (bf16 elems)
__global__ __launch_bounds__(256) void k_gemm(const float* __restrict__ x,
                                              const unsigned short* __restrict__ abt,
                                              const float* __restrict__ invn,
                                              float* __restrict__ out) {
    __shared__ unsigned short As[128 * BKP];
    __shared__ unsigned short Bs[128 * BKP];
    const int tid = threadIdx.x;
    const int cb = blockIdx.x;          // 0..3  (64 out-cols each)
    const int rb = blockIdx.y;          // 0..511
    const int lane = tid & 63, w = tid >> 6;

    f32x4 acc[16];
    #pragma unroll
    for (int i = 0; i < 16; i++) acc[i] = (f32x4){0.f, 0.f, 0.f, 0.f};

    for (int kb = 0; kb < 2; kb++) {
        __syncthreads();
        // stage x tile (128x128 fp32 -> normalize -> bf16)
        #pragma unroll
        for (int it = 0; it < 16; it++) {
            int flat = tid + it * 256;            // 128 rows x 32 float4
            int r = flat >> 5, c4 = flat & 31;
            f32x4 v = *(const f32x4*)&x[(size_t)(rb * 128 + r) * 256 + kb * 128 + c4 * 4];
            float sc = invn[rb * 128 + r];
            v[0] *= sc; v[1] *= sc; v[2] *= sc; v[3] *= sc;
            unsigned short h0 = f2bf(v[0]), h1 = f2bf(v[1]);
            unsigned short h2 = f2bf(v[2]), h3 = f2bf(v[3]);
            u32x2 pk = { (unsigned)h0 | ((unsigned)h1 << 16),
                         (unsigned)h2 | ((unsigned)h3 << 16) };
            *(u32x2*)&As[r * BKP + c4 * 4] = pk;
        }
        // stage Bt tile: rows 0..63 from AT[cb*64..], rows 64..127 from BT[cb*64..]
        #pragma unroll
        for (int it = 0; it < 8; it++) {
            int flat = tid + it * 256;            // 128 rows x 16 chunks(8 bf16)
            int r = flat >> 4, c8 = flat & 15;
            int gr = (r < 64) ? (cb * 64 + r) : (256 + cb * 64 + (r - 64));
            u32x4 vv = *(const u32x4*)&abt[(size_t)gr * 256 + kb * 128 + c8 * 8];
            *(u32x4*)&Bs[r * BKP + c8 * 8] = vv;
        }
        __syncthreads();
        #pragma unroll
        for (int ks = 0; ks < 4; ks++) {
            const int k0 = ks * 32 + (lane >> 4) * 8;
            s16x8 a[2], b[8];
            #pragma unroll
            for (int tm = 0; tm < 2; tm++)
                a[tm] = *(const s16x8*)&As[(w * 32 + tm * 16 + (lane & 15)) * BKP + k0];
            #pragma unroll
            for (int tn = 0; tn < 8; tn++)
                b[tn] = *(const s16x8*)&Bs[(tn * 16 + (lane & 15)) * BKP + k0];
            #pragma unroll
            for (int tm = 0; tm < 2; tm++)
                #pragma unroll
                for (int tn = 0; tn < 8; tn++)
                    acc[tm * 8 + tn] = __builtin_amdgcn_mfma_f32_16x16x32_bf16(
                        a[tm], b[tn], acc[tm * 8 + tn], 0, 0, 0);
        }
    }

    // epilogue: C/D layout col = lane&15, row = (lane>>4)*4 + reg
    const int qr = lane >> 4, c = lane & 15;
    #pragma unroll
    for (int tm = 0; tm < 2; tm++) {
        #pragma unroll
        for (int tn = 0; tn < 4; tn++) {
            f32x4 p = acc[tm * 8 + tn];
            f32x4 q = acc[tm * 8 + tn + 4];
            #pragma unroll
            for (int r = 0; r < 4; r++) {
                int m = w * 32 + tm * 16 + qr * 4 + r;
                out[(size_t)(rb * 128 + m) * 256 + cb * 64 + tn * 16 + c] =
                    p[r] * p[r] + q[r] * q[r];
            }
        }
    }
}

// ---------------- host ------------------------------------------------------
extern "C" void kernel_launch(void* const* d_in, const int* in_sizes, int n_in,
                              void* d_out, int out_size, void* d_ws, size_t ws_size,
                              hipStream_t stream) {
    (void)in_sizes; (void)n_in; (void)out_size; (void)ws_size;
    const float* x      = (const float*)d_in[0];
    const float* rots1  = (const float*)d_in[1];
    const float* phases = (const float*)d_in[2];
    const float* rots2  = (const float*)d_in[3];
    float* out = (float*)d_out;
    char* ws = (char*)d_ws;

    float2*         cs    = (float2*)(ws + OFF_CS);
    float*          ping  = (float*)(ws + OFF_PING);
    float*          pong  = (float*)(ws + OFF_PONG);
    unsigned short* abt   = (unsigned short*)(ws + OFF_ABT);
    float*          invn  = (float*)(ws + OFF_INV);

    k_cossin<<<(2 * NROT + 255) / 256, 256, 0, stream>>>(rots1, rots2, cs);
    k_blocks<<<dim3(4, PBLK, 2), 64, 0, stream>>>(cs, ping);
    k_combine<<<dim3(16, 16), 256, 0, stream>>>(ping, pong, 8);  // 16 -> 8 per set
    k_combine<<<dim3(16, 8),  256, 0, stream>>>(pong, ping, 4);  // 8 -> 4
    k_combine<<<dim3(16, 4),  256, 0, stream>>>(ping, pong, 2);  // 4 -> 2
    k_combine<<<dim3(16, 2),  256, 0, stream>>>(pong, ping, 1);  // 2 -> 1 (M1, M2)
    k_abt<<<dim3(16, 2), 256, 0, stream>>>(ping, phases, abt);
    k_norm<<<BATCH / 4, 256, 0, stream>>>(x, invn);
    k_gemm<<<dim3(4, BATCH / 128), 256, 0, stream>>>(x, abt, invn, out);
}

// Round 3
// 326.841 us; speedup vs baseline: 1.3516x; 1.3516x over previous
//
#include <hip/hip_runtime.h>
#include <stdint.h>

#define NDIM 256
#define BATCH 65536
#define NROT 32640          // 256*255/2
#define PBLK 16             // parallel Givens blocks per matrix

typedef float  f32x4 __attribute__((ext_vector_type(4)));
typedef short  s16x8 __attribute__((ext_vector_type(8)));
typedef unsigned int u32x4 __attribute__((ext_vector_type(4)));
typedef unsigned int u32x2 __attribute__((ext_vector_type(2)));

// round-to-nearest-even float -> bf16 bits
static __device__ __forceinline__ unsigned short f2bf(float f) {
    unsigned int u = __float_as_uint(f);
    u += 0x7fffu + ((u >> 16) & 1u);
    return (unsigned short)(u >> 16);
}

// ---------------- workspace layout (bytes) ----------------
static constexpr size_t OFF_CS   = 0;
static constexpr size_t OFF_PING = 524288;
static constexpr size_t OFF_PONG = OFF_PING + 8388608;
static constexpr size_t OFF_ABT  = OFF_PONG + 8388608;
static constexpr size_t OFF_INV  = OFF_ABT + 262144;
static constexpr size_t OFF_XBF  = OFF_INV + 262144;                 // 32 MB bf16 x
static constexpr size_t WS_BIG   = OFF_XBF + (size_t)BATCH * 256 * 2;

// ---------------- kernel 1: cos/sin of all rotation angles ----------------
__global__ void k_cossin(const float* __restrict__ r1, const float* __restrict__ r2,
                         float2* __restrict__ cs) {
    int i = blockIdx.x * 256 + threadIdx.x;
    if (i < 2 * NROT) {
        float th = (i < NROT) ? r1[i] : r2[i - NROT];
        cs[i] = make_float2(cosf(th), sinf(th));
    }
}

// ---------------- kernel 2: build PBLK partial Givens products per matrix ----
// One thread per column, column state in LDS, active-sweep row in a register.
// ALL of this block's cos/sin pairs are staged into LDS once up front
// (max 2259 pairs = 18 KB), so the rotation loop is branch-free pure LDS:
// the compiler can pipeline the colb reads ahead of the 1-FMA u-chain.
__global__ __launch_bounds__(64) void k_blocks(const float2* __restrict__ cs,
                                               float* __restrict__ bmats) {
    __shared__ float colb[256 * 64];
    __shared__ float2 csb[2304];        // >= max block nrot (2259)
    const int t = threadIdx.x;          // column within chunk
    const int chunk = blockIdx.x;       // 0..3 (64 cols each)
    const int b = blockIdx.y;           // block 0..15
    const int set = blockIdx.z;         // 0 = rots1, 1 = rots2
    const int col0 = chunk * 64;

    // sweep-aligned partition boundaries
    const int tlo = b * (NROT / PBLK);
    const int thi = (b + 1) * (NROT / PBLK);
    int s0 = -1, s1 = -1, roff = 0, rend = 0;
    {
        int cum = 0;
        for (int i = 0; i <= 255; i++) {
            if (s0 < 0 && cum >= tlo) { s0 = i; roff = cum; }
            if (s1 < 0 && cum >= thi) { s1 = i; rend = cum; }
            cum += 255 - i;
        }
        if (s1 < 0) { s1 = 255; rend = NROT; }
    }
    const int nrot = rend - roff;

    // stage ALL cos/sin pairs for this block (coalesced, fully pipelined)
    const float2* mycs = cs + (size_t)set * NROT + roff;
    for (int k = t; k < nrot; k += 64) csb[k] = mycs[k];

    // init identity (this WG's 64 columns)
    {
        const f32x4 z = {0.f, 0.f, 0.f, 0.f};
        #pragma unroll 8
        for (int q = 0; q < 64; q++)
            *(f32x4*)&colb[(q * 64 + t) * 4] = z;
        colb[(col0 + t) * 64 + t] = 1.0f;
    }
    __syncthreads();   // single wave: cheap; orders csb/colb writes vs reads

    int idx = 0;
    for (int i = s0; i < s1; i++) {
        float u = colb[i * 64 + t];
        const int n = 255 - i;
        const float2* sweep = &csb[idx];
        #pragma unroll 8
        for (int k = 0; k < n; k++) {
            float2 cv = sweep[k];
            float rj = colb[(i + 1 + k) * 64 + t];
            colb[(i + 1 + k) * 64 + t] = cv.y * u + cv.x * rj;  // new row j
            u = cv.x * u - cv.y * rj;                           // new row i
        }
        idx += n;
        colb[i * 64 + t] = u;
    }

    float* outm = bmats + (size_t)(set * PBLK + b) * 65536;
    for (int r = 0; r < 256; r++)
        outm[(size_t)r * 256 + col0 + t] = colb[r * 64 + t];
}

// ---------------- kernel 3: pairwise combine round (fp32 256^3 matmul) ------
__global__ __launch_bounds__(256) void k_combine(const float* __restrict__ src,
                                                 float* __restrict__ dst, int half) {
    const int by = blockIdx.y;
    const int set = by / half, pidx = by % half;
    const float* Am = src + (size_t)(set * 2 * half + 2 * pidx + 1) * 65536;
    const float* Bm = src + (size_t)(set * 2 * half + 2 * pidx) * 65536;
    float* Dm = dst + (size_t)(set * half + pidx) * 65536;
    const int tr = blockIdx.x >> 2, tc = blockIdx.x & 3;

    __shared__ float As[64 * 32];
    __shared__ float Bs[32 * 64];
    const int tid = threadIdx.x;
    const int tx = tid & 15, ty = tid >> 4;

    float acc[4][4] = {};
    for (int kb = 0; kb < 8; kb++) {
        __syncthreads();
        #pragma unroll
        for (int it = 0; it < 2; it++) {
            int flat = tid + it * 256;
            int r = flat >> 3, c4 = flat & 7;
            f32x4 v = *(const f32x4*)&Am[(size_t)(tr * 64 + r) * 256 + kb * 32 + c4 * 4];
            *(f32x4*)&As[r * 32 + c4 * 4] = v;
        }
        #pragma unroll
        for (int it = 0; it < 2; it++) {
            int flat = tid + it * 256;
            int r = flat >> 4, c4 = flat & 15;
            f32x4 v = *(const f32x4*)&Bm[(size_t)(kb * 32 + r) * 256 + tc * 64 + c4 * 4];
            *(f32x4*)&Bs[r * 64 + c4 * 4] = v;
        }
        __syncthreads();
        #pragma unroll 8
        for (int kk = 0; kk < 32; kk++) {
            f32x4 bv = *(const f32x4*)&Bs[kk * 64 + tx * 4];
            float a0 = As[(ty * 4 + 0) * 32 + kk];
            float a1 = As[(ty * 4 + 1) * 32 + kk];
            float a2 = As[(ty * 4 + 2) * 32 + kk];
            float a3 = As[(ty * 4 + 3) * 32 + kk];
            #pragma unroll
            for (int j = 0; j < 4; j++) {
                acc[0][j] += a0 * bv[j];
                acc[1][j] += a1 * bv[j];
                acc[2][j] += a2 * bv[j];
                acc[3][j] += a3 * bv[j];
            }
        }
    }
    #pragma unroll
    for (int i = 0; i < 4; i++) {
        f32x4 v = { acc[i][0], acc[i][1], acc[i][2], acc[i][3] };
        *(f32x4*)&Dm[(size_t)(tr * 64 + ty * 4 + i) * 256 + tc * 64 + tx * 4] = v;
    }
}

// ---------------- kernel 4: AT/BT = M2 @ diag(cos|sin(phases)) @ M1 -> bf16 -
__global__ __launch_bounds__(256) void k_abt(const float* __restrict__ mats,
                                             const float* __restrict__ phases,
                                             unsigned short* __restrict__ abt) {
    const float* Am = mats + 65536;    // M2
    const float* Bm = mats;            // M1
    const int v = blockIdx.y;          // 0: cos (AT), 1: sin (BT)
    const int tr = blockIdx.x >> 2, tc = blockIdx.x & 3;

    __shared__ float As[64 * 32];
    __shared__ float Bs[32 * 64];
    const int tid = threadIdx.x;
    const int tx = tid & 15, ty = tid >> 4;

    float acc[4][4] = {};
    for (int kb = 0; kb < 8; kb++) {
        __syncthreads();
        #pragma unroll
        for (int it = 0; it < 2; it++) {
            int flat = tid + it * 256;
            int r = flat >> 3, c4 = flat & 7;
            f32x4 vv = *(const f32x4*)&Am[(size_t)(tr * 64 + r) * 256 + kb * 32 + c4 * 4];
            *(f32x4*)&As[r * 32 + c4 * 4] = vv;
        }
        #pragma unroll
        for (int it = 0; it < 2; it++) {
            int flat = tid + it * 256;
            int r = flat >> 4, c4 = flat & 15;
            int kg = kb * 32 + r;
            float ph = phases[kg];
            float sc = v ? sinf(ph) : cosf(ph);
            f32x4 vv = *(const f32x4*)&Bm[(size_t)kg * 256 + tc * 64 + c4 * 4];
            vv[0] *= sc; vv[1] *= sc; vv[2] *= sc; vv[3] *= sc;
            *(f32x4*)&Bs[r * 64 + c4 * 4] = vv;
        }
        __syncthreads();
        #pragma unroll 8
        for (int kk = 0; kk < 32; kk++) {
            f32x4 bv = *(const f32x4*)&Bs[kk * 64 + tx * 4];
            float a0 = As[(ty * 4 + 0) * 32 + kk];
            float a1 = As[(ty * 4 + 1) * 32 + kk];
            float a2 = As[(ty * 4 + 2) * 32 + kk];
            float a3 = As[(ty * 4 + 3) * 32 + kk];
            #pragma unroll
            for (int j = 0; j < 4; j++) {
                acc[0][j] += a0 * bv[j];
                acc[1][j] += a1 * bv[j];
                acc[2][j] += a2 * bv[j];
                acc[3][j] += a3 * bv[j];
            }
        }
    }
    #pragma unroll
    for (int i = 0; i < 4; i++) {
        unsigned short h0 = f2bf(acc[i][0]), h1 = f2bf(acc[i][1]);
        unsigned short h2 = f2bf(acc[i][2]), h3 = f2bf(acc[i][3]);
        u32x2 pk = { (unsigned)h0 | ((unsigned)h1 << 16),
                     (unsigned)h2 | ((unsigned)h3 << 16) };
        *(u32x2*)&abt[(size_t)(v * 256 + tr * 64 + ty * 4 + i) * 256 + tc * 64 + tx * 4] = pk;
    }
}

// ---------------- kernel 5a: normalize rows -> bf16 (fast path) -------------
__global__ __launch_bounds__(256) void k_xnorm(const float* __restrict__ x,
                                               unsigned short* __restrict__ xbf) {
    const int row = blockIdx.x * 4 + (threadIdx.x >> 6);
    const int lane = threadIdx.x & 63;
    f32x4 v = *(const f32x4*)&x[(size_t)row * 256 + lane * 4];
    float s = v[0] * v[0] + v[1] * v[1] + v[2] * v[2] + v[3] * v[3];
    for (int off = 32; off; off >>= 1) s += __shfl_xor(s, off, 64);
    float sc = 1.0f / sqrtf(s);
    unsigned short h0 = f2bf(v[0] * sc), h1 = f2bf(v[1] * sc);
    unsigned short h2 = f2bf(v[2] * sc), h3 = f2bf(v[3] * sc);
    u32x2 pk = { (unsigned)h0 | ((unsigned)h1 << 16),
                 (unsigned)h2 | ((unsigned)h3 << 16) };
    *(u32x2*)&xbf[(size_t)row * 256 + lane * 4] = pk;
}

// ---------------- kernel 5b: per-row 1/||x|| (fallback path) ----------------
__global__ __launch_bounds__(256) void k_norm(const float* __restrict__ x,
                                              float* __restrict__ invn) {
    const int row = blockIdx.x * 4 + (threadIdx.x >> 6);
    const int lane = threadIdx.x & 63;
    f32x4 v = *(const f32x4*)&x[(size_t)row * 256 + lane * 4];
    float s = v[0] * v[0] + v[1] * v[1] + v[2] * v[2] + v[3] * v[3];
    for (int off = 32; off; off >>= 1) s += __shfl_xor(s, off, 64);
    if (lane == 0) invn[row] = 1.0f / sqrtf(s);
}

// ---------------- kernel 6a: GEMM + |.|^2 from pre-converted bf16 x ---------
#define BKP 136   // padded LDS k-stride (bf16 elems)
__global__ __launch_bounds__(256) void k_gemm_bf(const unsigned short* __restrict__ xbf,
                                                 const unsigned short* __restrict__ abt,
                                                 float* __restrict__ out) {
    __shared__ unsigned short As[128 * BKP];
    __shared__ unsigned short Bs[128 * BKP];
    const int tid = threadIdx.x;
    const int cb = blockIdx.x;          // 0..3  (64 out-cols each)
    const int rb = blockIdx.y;          // 0..511
    const int lane = tid & 63, w = tid >> 6;

    f32x4 acc[16];
    #pragma unroll
    for (int i = 0; i < 16; i++) acc[i] = (f32x4){0.f, 0.f, 0.f, 0.f};

    for (int kb = 0; kb < 2; kb++) {
        __syncthreads();
        // stage x tile (128x128 bf16, 16B vector loads)
        #pragma unroll
        for (int it = 0; it < 8; it++) {
            int flat = tid + it * 256;            // 128 rows x 16 chunks(8 bf16)
            int r = flat >> 4, c8 = flat & 15;
            u32x4 vv = *(const u32x4*)&xbf[(size_t)(rb * 128 + r) * 256 + kb * 128 + c8 * 8];
            *(u32x4*)&As[r * BKP + c8 * 8] = vv;
        }
        // stage Bt tile: rows 0..63 from AT[cb*64..], rows 64..127 from BT[cb*64..]
        #pragma unroll
        for (int it = 0; it < 8; it++) {
            int flat = tid + it * 256;
            int r = flat >> 4, c8 = flat & 15;
            int gr = (r < 64) ? (cb * 64 + r) : (256 + cb * 64 + (r - 64));
            u32x4 vv = *(const u32x4*)&abt[(size_t)gr * 256 + kb * 128 + c8 * 8];
            *(u32x4*)&Bs[r * BKP + c8 * 8] = vv;
        }
        __syncthreads();
        #pragma unroll
        for (int ks = 0; ks < 4; ks++) {
            const int k0 = ks * 32 + (lane >> 4) * 8;
            s16x8 a[2], b[8];
            #pragma unroll
            for (int tm = 0; tm < 2; tm++)
                a[tm] = *(const s16x8*)&As[(w * 32 + tm * 16 + (lane & 15)) * BKP + k0];
            #pragma unroll
            for (int tn = 0; tn < 8; tn++)
                b[tn] = *(const s16x8*)&Bs[(tn * 16 + (lane & 15)) * BKP + k0];
            #pragma unroll
            for (int tm = 0; tm < 2; tm++)
                #pragma unroll
                for (int tn = 0; tn < 8; tn++)
                    acc[tm * 8 + tn] = __builtin_amdgcn_mfma_f32_16x16x32_bf16(
                        a[tm], b[tn], acc[tm * 8 + tn], 0, 0, 0);
        }
    }

    // epilogue: C/D layout col = lane&15, row = (lane>>4)*4 + reg
    const int qr = lane >> 4, c = lane & 15;
    #pragma unroll
    for (int tm = 0; tm < 2; tm++) {
        #pragma unroll
        for (int tn = 0; tn < 4; tn++) {
            f32x4 p = acc[tm * 8 + tn];
            f32x4 q = acc[tm * 8 + tn + 4];
            #pragma unroll
            for (int r = 0; r < 4; r++) {
                int m = w * 32 + tm * 16 + qr * 4 + r;
                out[(size_t)(rb * 128 + m) * 256 + cb * 64 + tn * 16 + c] =
                    p[r] * p[r] + q[r] * q[r];
            }
        }
    }
}

// ---------------- kernel 6b: GEMM + |.|^2 from fp32 x (fallback) ------------
__global__ __launch_bounds__(256) void k_gemm_f32(const float* __restrict__ x,
                                                  const unsigned short* __restrict__ abt,
                                                  const float* __restrict__ invn,
                                                  float* __restrict__ out) {
    __shared__ unsigned short As[128 * BKP];
    __shared__ unsigned short Bs[128 * BKP];
    const int tid = threadIdx.x;
    const int cb = blockIdx.x;
    const int rb = blockIdx.y;
    const int lane = tid & 63, w = tid >> 6;

    f32x4 acc[16];
    #pragma unroll
    for (int i = 0; i < 16; i++) acc[i] = (f32x4){0.f, 0.f, 0.f, 0.f};

    for (int kb = 0; kb < 2; kb++) {
        __syncthreads();
        #pragma unroll
        for (int it = 0; it < 16; it++) {
            int flat = tid + it * 256;
            int r = flat >> 5, c4 = flat & 31;
            f32x4 v = *(const f32x4*)&x[(size_t)(rb * 128 + r) * 256 + kb * 128 + c4 * 4];
            float sc = invn[rb * 128 + r];
            v[0] *= sc; v[1] *= sc; v[2] *= sc; v[3] *= sc;
            unsigned short h0 = f2bf(v[0]), h1 = f2bf(v[1]);
            unsigned short h2 = f2bf(v[2]), h3 = f2bf(v[3]);
            u32x2 pk = { (unsigned)h0 | ((unsigned)h1 << 16),
                         (unsigned)h2 | ((unsigned)h3 << 16) };
            *(u32x2*)&As[r * BKP + c4 * 4] = pk;
        }
        #pragma unroll
        for (int it = 0; it < 8; it++) {
            int flat = tid + it * 256;
            int r = flat >> 4, c8 = flat & 15;
            int gr = (r < 64) ? (cb * 64 + r) : (256 + cb * 64 + (r - 64));
            u32x4 vv = *(const u32x4*)&abt[(size_t)gr * 256 + kb * 128 + c8 * 8];
            *(u32x4*)&Bs[r * BKP + c8 * 8] = vv;
        }
        __syncthreads();
        #pragma unroll
        for (int ks = 0; ks < 4; ks++) {
            const int k0 = ks * 32 + (lane >> 4) * 8;
            s16x8 a[2], b[8];
            #pragma unroll
            for (int tm = 0; tm < 2; tm++)
                a[tm] = *(const s16x8*)&As[(w * 32 + tm * 16 + (lane & 15)) * BKP + k0];
            #pragma unroll
            for (int tn = 0; tn < 8; tn++)
                b[tn] = *(const s16x8*)&Bs[(tn * 16 + (lane & 15)) * BKP + k0];
            #pragma unroll
            for (int tm = 0; tm < 2; tm++)
                #pragma unroll
                for (int tn = 0; tn < 8; tn++)
                    acc[tm * 8 + tn] = __builtin_amdgcn_mfma_f32_16x16x32_bf16(
                        a[tm], b[tn], acc[tm * 8 + tn], 0, 0, 0);
        }
    }

    const int qr = lane >> 4, c = lane & 15;
    #pragma unroll
    for (int tm = 0; tm < 2; tm++) {
        #pragma unroll
        for (int tn = 0; tn < 4; tn++) {
            f32x4 p = acc[tm * 8 + tn];
            f32x4 q = acc[tm * 8 + tn + 4];
            #pragma unroll
            for (int r = 0; r < 4; r++) {
                int m = w * 32 + tm * 16 + qr * 4 + r;
                out[(size_t)(rb * 128 + m) * 256 + cb * 64 + tn * 16 + c] =
                    p[r] * p[r] + q[r] * q[r];
            }
        }
    }
}

// ---------------- host ------------------------------------------------------
extern "C" void kernel_launch(void* const* d_in, const int* in_sizes, int n_in,
                              void* d_out, int out_size, void* d_ws, size_t ws_size,
                              hipStream_t stream) {
    (void)in_sizes; (void)n_in; (void)out_size;
    const float* x      = (const float*)d_in[0];
    const float* rots1  = (const float*)d_in[1];
    const float* phases = (const float*)d_in[2];
    const float* rots2  = (const float*)d_in[3];
    float* out = (float*)d_out;
    char* ws = (char*)d_ws;

    float2*         cs    = (float2*)(ws + OFF_CS);
    float*          ping  = (float*)(ws + OFF_PING);
    float*          pong  = (float*)(ws + OFF_PONG);
    unsigned short* abt   = (unsigned short*)(ws + OFF_ABT);
    float*          invn  = (float*)(ws + OFF_INV);
    unsigned short* xbf   = (unsigned short*)(ws + OFF_XBF);

    k_cossin<<<(2 * NROT + 255) / 256, 256, 0, stream>>>(rots1, rots2, cs);
    k_blocks<<<dim3(4, PBLK, 2), 64, 0, stream>>>(cs, ping);
    k_combine<<<dim3(16, 16), 256, 0, stream>>>(ping, pong, 8);  // 16 -> 8 per set
    k_combine<<<dim3(16, 8),  256, 0, stream>>>(pong, ping, 4);  // 8 -> 4
    k_combine<<<dim3(16, 4),  256, 0, stream>>>(ping, pong, 2);  // 4 -> 2
    k_combine<<<dim3(16, 2),  256, 0, stream>>>(pong, ping, 1);  // 2 -> 1 (M1, M2)
    k_abt<<<dim3(16, 2), 256, 0, stream>>>(ping, phases, abt);

    if (ws_size >= WS_BIG) {
        k_xnorm<<<BATCH / 4, 256, 0, stream>>>(x, xbf);
        k_gemm_bf<<<dim3(4, BATCH / 128), 256, 0, stream>>>(xbf, abt, out);
    } else {
        k_norm<<<BATCH / 4, 256, 0, stream>>>(x, invn);
        k_gemm_f32<<<dim3(4, BATCH / 128), 256, 0, stream>>>(x, abt, invn, out);
    }
}